// Round 8
// baseline (115.245 us; speedup 1.0000x reference)
//
#include <hip/hip_runtime.h>
#include <cstddef>
#include <cstdint>

#define POS_LEN    32768
#define NUM_NEG    64
#define N_RULES    262144
#define N_UNLABEL  131072
#define NUM_ENT    100000
#define NUM_REL    500
#define EMB_DIM    256
#define WEIGHT_DECAY 1e-5

#define AUX_BLOCKS    2048
#define GATHER_BLOCKS 2048
#define LOSS_BLOCKS   1024

#define NWAVE   (GATHER_BLOCKS * 4)          // 8192 waves
#define R_ITERS (N_RULES / 4 / NWAVE)        // 8
#define U_ITERS (N_UNLABEL / 4 / NWAVE)      // 4

typedef __attribute__((ext_vector_type(4))) float        f32x4;
typedef __attribute__((ext_vector_type(2))) unsigned int u32x2;
typedef __attribute__((ext_vector_type(4))) unsigned int u32x4;

__device__ __forceinline__ float softplusf_(float x) {
    return fmaxf(x, 0.0f) + log1pf(expf(-fabsf(x)));
}
__device__ __forceinline__ float sigmoidf_(float x) {
    return 1.0f / (1.0f + expf(-x));
}
__device__ __forceinline__ float quarter_sum16(float v) {   // reduce within 16-lane group
#pragma unroll
    for (int m = 1; m <= 8; m <<= 1) v += __shfl_xor(v, m, 64);
    return v;
}
__device__ __forceinline__ float wave_sum64(float v) {
#pragma unroll
    for (int m = 32; m >= 1; m >>= 1) v += __shfl_xor(v, m, 64);
    return v;
}
__device__ __forceinline__ double wave_sum64d(double v) {
#pragma unroll
    for (int m = 32; m >= 1; m >>= 1) v += __shfl_xor(v, m, 64);
    return v;
}

// ---- fp8 (OCP e4m3) pack/unpack via gfx950 HW converts (proven R4/R7) ----
__device__ __forceinline__ u32x2 f32x8_to_fp8(const f32x4 a, const f32x4 b) {
    int lo = 0, hi = 0;
    lo = __builtin_amdgcn_cvt_pk_fp8_f32(a[0], a[1], lo, false);
    lo = __builtin_amdgcn_cvt_pk_fp8_f32(a[2], a[3], lo, true);
    hi = __builtin_amdgcn_cvt_pk_fp8_f32(b[0], b[1], hi, false);
    hi = __builtin_amdgcn_cvt_pk_fp8_f32(b[2], b[3], hi, true);
    u32x2 r; r[0] = (unsigned)lo; r[1] = (unsigned)hi; return r;
}
__device__ __forceinline__ void fp8x4_to_f32(unsigned int w, float* o) {
    auto x = __builtin_amdgcn_cvt_pk_f32_fp8((int)w, false);
    auto y = __builtin_amdgcn_cvt_pk_f32_fp8((int)w, true);
    o[0] = x[0]; o[1] = x[1]; o[2] = y[0]; o[3] = y[1];
}

// Quarter-wave tri-product over 16 fp8 elems/lane (16 lanes x 16 = 256 dims).
__device__ __forceinline__ float dot3_q(const u32x4 hv, const u32x4 rv, const u32x4 tv) {
    float s = 0.0f;
#pragma unroll
    for (int w = 0; w < 4; ++w) {
        float hf[4], rf[4], tf[4];
        fp8x4_to_f32(hv[w], hf);
        fp8x4_to_f32(rv[w], rf);
        fp8x4_to_f32(tv[w], tf);
        s = fmaf(hf[0] * rf[0], tf[0], s);
        s = fmaf(hf[1] * rf[1], tf[1], s);
        s = fmaf(hf[2] * rf[2], tf[2], s);
        s = fmaf(hf[3] * rf[3], tf[3], s);
    }
    return quarter_sum16(s);
}

// ---- Kernel 1: quantize ent/rel -> fp8 (16 floats/iter), f32 sum-of-squares,
//      zero pi_grad. Per-block partial slots, no atomics. ----
__global__ __launch_bounds__(256) void aux_fp8_kernel(const float* __restrict__ ent,
                                                      const float* __restrict__ rel,
                                                      u32x4* __restrict__ ent8,
                                                      u32x4* __restrict__ rel8,
                                                      float* __restrict__ pi_grad,
                                                      float* __restrict__ auxp) {
    const int tid = blockIdx.x * blockDim.x + threadIdx.x;
    const int stride = gridDim.x * blockDim.x;
    for (int i = tid; i < N_UNLABEL; i += stride) pi_grad[i] = 0.0f;

    float sq = 0.0f;
    const f32x4* entv = reinterpret_cast<const f32x4*>(ent);
    for (int i = tid; i < (NUM_ENT * EMB_DIM) / 16; i += stride) {
        f32x4 a = __builtin_nontemporal_load(entv + (size_t)i * 4);
        f32x4 b = __builtin_nontemporal_load(entv + (size_t)i * 4 + 1);
        f32x4 c = __builtin_nontemporal_load(entv + (size_t)i * 4 + 2);
        f32x4 d = __builtin_nontemporal_load(entv + (size_t)i * 4 + 3);
        sq += a[0]*a[0] + a[1]*a[1] + a[2]*a[2] + a[3]*a[3]
            + b[0]*b[0] + b[1]*b[1] + b[2]*b[2] + b[3]*b[3]
            + c[0]*c[0] + c[1]*c[1] + c[2]*c[2] + c[3]*c[3]
            + d[0]*d[0] + d[1]*d[1] + d[2]*d[2] + d[3]*d[3];
        u32x2 lo = f32x8_to_fp8(a, b);
        u32x2 hi = f32x8_to_fp8(c, d);
        u32x4 o; o[0] = lo[0]; o[1] = lo[1]; o[2] = hi[0]; o[3] = hi[1];
        ent8[i] = o;
    }
    const f32x4* relv = reinterpret_cast<const f32x4*>(rel);
    for (int i = tid; i < (NUM_REL * EMB_DIM) / 16; i += stride) {
        f32x4 a = __builtin_nontemporal_load(relv + (size_t)i * 4);
        f32x4 b = __builtin_nontemporal_load(relv + (size_t)i * 4 + 1);
        f32x4 c = __builtin_nontemporal_load(relv + (size_t)i * 4 + 2);
        f32x4 d = __builtin_nontemporal_load(relv + (size_t)i * 4 + 3);
        sq += a[0]*a[0] + a[1]*a[1] + a[2]*a[2] + a[3]*a[3]
            + b[0]*b[0] + b[1]*b[1] + b[2]*b[2] + b[3]*b[3]
            + c[0]*c[0] + c[1]*c[1] + c[2]*c[2] + c[3]*c[3]
            + d[0]*d[0] + d[1]*d[1] + d[2]*d[2] + d[3]*d[3];
        u32x2 lo = f32x8_to_fp8(a, b);
        u32x2 hi = f32x8_to_fp8(c, d);
        u32x4 o; o[0] = lo[0]; o[1] = lo[1]; o[2] = hi[0]; o[3] = hi[1];
        rel8[i] = o;
    }
    sq = wave_sum64(sq);
    __shared__ float ls[8];
    const int lane = threadIdx.x & 63, wid = threadIdx.x >> 6;
    if (lane == 0) ls[wid] = sq;
    __syncthreads();
    if (threadIdx.x == 0) {
        float bs = 0.0f;
        for (int w = 0; w < (int)(blockDim.x >> 6); ++w) bs += ls[w];
        auxp[blockIdx.x] = bs;
    }
}

// ---- Kernel 2: fused fp8 gathers, quarter-wave (4 triples/wave).
// Rules loop is software-pipelined (indices prefetched one iter ahead);
// unlabel loop unrolled x2. Compile-time trip counts. ----
__global__ __launch_bounds__(256, 8) void gather_kernel(const float* __restrict__ conf,
                                                        const u32x4* __restrict__ ent8,
                                                        const u32x4* __restrict__ rel8,
                                                        const int* __restrict__ p1,
                                                        const int* __restrict__ p2,
                                                        const int* __restrict__ tnum,
                                                        const int* __restrict__ uids,
                                                        const int* __restrict__ ut,
                                                        float* __restrict__ pi_grad,
                                                        float* __restrict__ su_out) {
    const int lane = threadIdx.x & 63;
    const int l    = lane & 15;
    const int q    = lane >> 4;   // quarter 0..3
    const int wave = blockIdx.x * 4 + (threadIdx.x >> 6);

    // ---------- rules: 8 iterations, index-prefetch pipeline ----------
    int rule = wave * 4 + q;
    int h1 = __builtin_nontemporal_load(p1 + rule * 3);
    int r1 = __builtin_nontemporal_load(p1 + rule * 3 + 1);
    int t1 = __builtin_nontemporal_load(p1 + rule * 3 + 2);
    int tn = __builtin_nontemporal_load(tnum + rule);
    float cf = __builtin_nontemporal_load(conf + rule);
    int uid = __builtin_nontemporal_load(uids + rule);
    int h2 = 0, r2 = 0, t2 = 0;
    if (tn == 3) {
        h2 = __builtin_nontemporal_load(p2 + rule * 3);
        r2 = __builtin_nontemporal_load(p2 + rule * 3 + 1);
        t2 = __builtin_nontemporal_load(p2 + rule * 3 + 2);
    }
    for (int k = 0; k < R_ITERS; ++k) {
        const bool  has2  = (tn == 3);
        const float cf_c  = cf;
        const int   uid_c = uid;
        // issue all row loads for current iteration
        const u32x4 H1 = ent8[(size_t)h1 * 16 + l];
        const u32x4 R1 = rel8[(size_t)r1 * 16 + l];
        const u32x4 T1 = ent8[(size_t)t1 * 16 + l];
        u32x4 H2v = {0,0,0,0}, R2v = {0,0,0,0}, T2v = {0,0,0,0};
        if (has2) {
            H2v = ent8[(size_t)h2 * 16 + l];
            R2v = rel8[(size_t)r2 * 16 + l];
            T2v = ent8[(size_t)t2 * 16 + l];
        }
        // prefetch next iteration's indices while rows are in flight
        if (k + 1 < R_ITERS) {
            rule += NWAVE * 4;
            h1 = __builtin_nontemporal_load(p1 + rule * 3);
            r1 = __builtin_nontemporal_load(p1 + rule * 3 + 1);
            t1 = __builtin_nontemporal_load(p1 + rule * 3 + 2);
            tn = __builtin_nontemporal_load(tnum + rule);
            cf = __builtin_nontemporal_load(conf + rule);
            uid = __builtin_nontemporal_load(uids + rule);
            if (tn == 3) {
                h2 = __builtin_nontemporal_load(p2 + rule * 3);
                r2 = __builtin_nontemporal_load(p2 + rule * 3 + 1);
                t2 = __builtin_nontemporal_load(p2 + rule * 3 + 2);
            }
        }
        // compute with current rows
        float c = sigmoidf_(dot3_q(H1, R1, T1)) * cf_c;
        if (has2) c *= sigmoidf_(dot3_q(H2v, R2v, T2v));
        if (l == 0) atomicAdd(&pi_grad[uid_c], c);
    }

    // ---------- unlabel: 4 iterations, unrolled x2 ----------
    for (int k = 0; k < U_ITERS; k += 2) {
        const int i0 = (wave + k * NWAVE) * 4 + q;
        const int i1 = i0 + NWAVE * 4;
        const int ha = __builtin_nontemporal_load(ut + i0 * 3);
        const int ra = __builtin_nontemporal_load(ut + i0 * 3 + 1);
        const int ta = __builtin_nontemporal_load(ut + i0 * 3 + 2);
        const int hb = __builtin_nontemporal_load(ut + i1 * 3);
        const int rb = __builtin_nontemporal_load(ut + i1 * 3 + 1);
        const int tb = __builtin_nontemporal_load(ut + i1 * 3 + 2);
        const u32x4 HA = ent8[(size_t)ha * 16 + l];
        const u32x4 RA = rel8[(size_t)ra * 16 + l];
        const u32x4 TA = ent8[(size_t)ta * 16 + l];
        const u32x4 HB = ent8[(size_t)hb * 16 + l];
        const u32x4 RB = rel8[(size_t)rb * 16 + l];
        const u32x4 TB = ent8[(size_t)tb * 16 + l];
        const float sa = dot3_q(HA, RA, TA);
        const float sb = dot3_q(HB, RB, TB);
        if (l == 0) {
            su_out[i0] = sa;
            su_out[i1] = sb;
        }
    }
}

// ---- Kernel 3: unlabel loss + pos/neg softplus sums. Per-block partials. ----
__global__ __launch_bounds__(256) void loss_kernel(const float* __restrict__ su,
                                                   const float* __restrict__ pi_grad,
                                                   const float* __restrict__ pos,
                                                   const float* __restrict__ neg,
                                                   float* __restrict__ lossp) {
    const int tid = blockIdx.x * blockDim.x + threadIdx.x;
    const int stride = gridDim.x * blockDim.x;
    float ul = 0.0f, ps = 0.0f, ns = 0.0f;
    for (int i = tid; i < N_UNLABEL; i += stride) {
        const float s   = su[i];
        const float p   = sigmoidf_(s);
        const float tgt = fminf(fmaxf(p + pi_grad[i], 0.0f), 1.0f);
        ul += tgt * softplusf_(-s) + (1.0f - tgt) * softplusf_(s);
    }
    const f32x4* posv = reinterpret_cast<const f32x4*>(pos);
    for (int i = tid; i < POS_LEN / 4; i += stride) {
        f32x4 v = __builtin_nontemporal_load(posv + i);
        ps += softplusf_(-v[0]) + softplusf_(-v[1]) + softplusf_(-v[2]) + softplusf_(-v[3]);
    }
    const f32x4* negv = reinterpret_cast<const f32x4*>(neg);
    for (int i = tid; i < (POS_LEN * NUM_NEG) / 4; i += stride) {
        f32x4 v = __builtin_nontemporal_load(negv + i);
        ns += softplusf_(v[0]) + softplusf_(v[1]) + softplusf_(v[2]) + softplusf_(v[3]);
    }
    ul = wave_sum64(ul); ps = wave_sum64(ps); ns = wave_sum64(ns);
    __shared__ float lu[8], lp[8], ln[8];
    const int lane = threadIdx.x & 63, wid = threadIdx.x >> 6;
    if (lane == 0) { lu[wid] = ul; lp[wid] = ps; ln[wid] = ns; }
    __syncthreads();
    if (threadIdx.x == 0) {
        float bu = 0.0f, bp = 0.0f, bn = 0.0f;
        for (int w = 0; w < (int)(blockDim.x >> 6); ++w) { bu += lu[w]; bp += lp[w]; bn += ln[w]; }
        lossp[blockIdx.x]                   = bu;
        lossp[LOSS_BLOCKS + blockIdx.x]     = bp;
        lossp[2 * LOSS_BLOCKS + blockIdx.x] = bn;
    }
}

// ---- Kernel 4: single-wave finalize in f64. ----
__global__ void finalize_kernel(const float* __restrict__ auxp,
                                const float* __restrict__ lossp,
                                float* __restrict__ out) {
    const int lane = threadIdx.x;  // 64 threads
    double sq = 0.0, ul = 0.0, ps = 0.0, ns = 0.0;
    for (int i = lane; i < AUX_BLOCKS; i += 64) sq += (double)auxp[i];
    for (int i = lane; i < LOSS_BLOCKS; i += 64) {
        ul += (double)lossp[i];
        ps += (double)lossp[LOSS_BLOCKS + i];
        ns += (double)lossp[2 * LOSS_BLOCKS + i];
    }
    sq = wave_sum64d(sq); ul = wave_sum64d(ul);
    ps = wave_sum64d(ps); ns = wave_sum64d(ns);
    if (lane == 0) {
        double v = ps / (double)POS_LEN
                 + ns / ((double)POS_LEN * (double)NUM_NEG)
                 + ul / (double)N_UNLABEL
                 + WEIGHT_DECAY * sq;
        out[0] = (float)v;
    }
}

extern "C" void kernel_launch(void* const* d_in, const int* in_sizes, int n_in,
                              void* d_out, int out_size, void* d_ws, size_t ws_size,
                              hipStream_t stream) {
    const float* pos  = (const float*)d_in[0];
    const float* neg  = (const float*)d_in[1];
    const float* conf = (const float*)d_in[2];
    const float* ent  = (const float*)d_in[3];
    const float* rel  = (const float*)d_in[4];
    const int*   p1   = (const int*)d_in[5];
    const int*   p2   = (const int*)d_in[6];
    const int*   tnum = (const int*)d_in[7];
    const int*   uids = (const int*)d_in[8];
    const int*   ut   = (const int*)d_in[9];

    // ws layout (all regions written unconditionally every call)
    const size_t off_pi    = 0;                                      // 512 KB
    const size_t off_su    = off_pi + (size_t)N_UNLABEL * 4;         // 512 KB
    const size_t off_auxp  = off_su + (size_t)N_UNLABEL * 4;         // 8 KB
    const size_t off_lossp = off_auxp + (size_t)AUX_BLOCKS * 4;      // 12 KB
    const size_t off_tab   = (off_lossp + (size_t)3 * LOSS_BLOCKS * 4 + 511) & ~(size_t)511;
    const size_t off_rel8  = off_tab + (size_t)NUM_ENT * EMB_DIM;    // fp8: 1 B/elem

    float* pi_grad = (float*)((char*)d_ws + off_pi);
    float* su      = (float*)((char*)d_ws + off_su);
    float* auxp    = (float*)((char*)d_ws + off_auxp);
    float* lossp   = (float*)((char*)d_ws + off_lossp);
    u32x4* ent8    = (u32x4*)((char*)d_ws + off_tab);
    u32x4* rel8    = (u32x4*)((char*)d_ws + off_rel8);

    aux_fp8_kernel<<<AUX_BLOCKS, 256, 0, stream>>>(ent, rel, ent8, rel8, pi_grad, auxp);
    gather_kernel<<<GATHER_BLOCKS, 256, 0, stream>>>(conf, ent8, rel8,
                                                     p1, p2, tnum, uids, ut, pi_grad, su);
    loss_kernel<<<LOSS_BLOCKS, 256, 0, stream>>>(su, pi_grad, pos, neg, lossp);
    finalize_kernel<<<1, 64, 0, stream>>>(auxp, lossp, (float*)d_out);
}